// Round 6
// baseline (44.398 us; speedup 1.0000x reference)
//
#include <hip/hip_runtime.h>
#include <stdint.h>

// Blocksparse Deep ReLU GAM forward via chained f16 MFMA.
// 128 towers, each 2->16->12->8->1 MLP over input pair (2t, 2t+1);
// out[s] = sum_t tower_t(x[s]) + bias. shape_loss output = zeros(128).
//
// v_mfma_f32_16x16x16_f16 D layout (row=(lane>>4)*4+reg, col=lane&15)
// equals the B layout (k=(lane>>4)*4+i, col=lane&15), so Y = W·X chains
// layer-to-layer with only lane-local relu + f32->f16 cvt.
//
// Round 6: U=2 (32 samples/wave) -> 8192 waves (32/CU capacity) with
// launch_bounds(256,8); packed-f16 relu (cvt_pkrtz then v_pk_max_f16)
// cuts relu VALU 33%; B0 built with one cvt_pkrtz + constant high word.
//
// 4-tower shared B0: lane (kg,col) carries B0 rows 4kg..4kg+2 =
// {x[s][2(tb+kg)], x[s][2(tb+kg)+1], 1}; tower tb+j's A0 is nonzero only
// in k-columns 4j..4j+2, so one coalesced all-lane x load feeds 4 towers.
//
// Bias: b0 -> A0 k=4j+2 (homogeneous coord); b1 -> C of layer-1 MFMA;
// b2 -> A2 column k=12 with h1[12]=1 (rows 12..15 of h1 are structurally
// zero); sum_t b3[t] + bias -> one scalar at the end.

constexpr int BATCH = 32768;
constexpr int FEAT  = 256;
constexpr int NTOW  = 128;
constexpr int U     = 2;    // 16-sample tiles per wave

constexpr int REC = 528;  // dwords per tower record
// record layout (dword offsets): A0=0, A1=128, A2=256, A3=384 (each 64
// lanes x uint2 in lane-major order), b1 compact f32[16] at 512.
constexpr int OFF_A1 = 128, OFF_A2 = 256, OFF_A3 = 384, OFF_B1 = 512;

typedef _Float16 h4_t __attribute__((ext_vector_type(4)));
typedef __fp16   hp2_t __attribute__((ext_vector_type(2)));
typedef float    f4_t __attribute__((ext_vector_type(4)));

static __device__ __forceinline__ void store_frag(uint32_t* dst, h4_t v) {
  union { h4_t h; uint2 u; } cv; cv.h = v;
  *(uint2*)dst = cv.u;
}
static __device__ __forceinline__ h4_t load_frag(const uint32_t* src) {
  union { uint2 u; h4_t h; } cv; cv.u = *(const uint2*)src;
  return cv.h;
}
// pack 4 f32 -> 4 f16 (2x v_cvt_pkrtz) then packed relu (2x v_pk_max_f16).
// relu(cvt(x)) == cvt(relu(x)): RTZ preserves sign; -0 is harmless in dots.
static __device__ __forceinline__ h4_t relu_pack4(const f4_t d) {
  const hp2_t lo = __builtin_amdgcn_cvt_pkrtz(d[0], d[1]);
  const hp2_t hi = __builtin_amdgcn_cvt_pkrtz(d[2], d[3]);
  h4_t r;
  r[0] = (_Float16)lo[0]; r[1] = (_Float16)lo[1];
  r[2] = (_Float16)hi[0]; r[3] = (_Float16)hi[1];
  const h4_t z = {(_Float16)0.f, (_Float16)0.f, (_Float16)0.f, (_Float16)0.f};
  return __builtin_elementwise_max(r, z);
}

__global__ void pack_frags(
    const float* __restrict__ W0, const float* __restrict__ B0,
    const float* __restrict__ W1, const float* __restrict__ B1,
    const float* __restrict__ W2, const float* __restrict__ B2,
    const float* __restrict__ W3, const float* __restrict__ B3,
    const float* __restrict__ bias, uint32_t* __restrict__ pack) {
  const int t   = blockIdx.x;
  const int l   = threadIdx.x;      // 64 threads = 64 lanes
  const int row = l & 15;           // A-frag row  = lane&15
  const int kg  = l >> 4;           // A-frag k    = (lane>>4)*4 + r
  uint32_t* rec = pack + t * REC;

  h4_t a0, a1, a2, a3;
#pragma unroll
  for (int r = 0; r < 4; ++r) {
    const int k = kg * 4 + r;
    // A0: tower t occupies k-columns 4*(t&3) .. 4*(t&3)+2.
    float v0 = 0.f;
    if (kg == (t & 3)) {
      if (r < 2)       v0 = W0[(16*t + row) * FEAT + 2*t + r];
      else if (r == 2) v0 = B0[16*t + row];
    }
    a0[r] = (_Float16)v0;

    float v1 = 0.f;
    if (row < 12)    v1 = W1[(12*t + row) * (16*NTOW) + 16*t + k];
    a1[r] = (_Float16)v1;

    float v2 = 0.f;
    if (row < 8) {
      if (k < 12)       v2 = W2[(8*t + row) * (12*NTOW) + 12*t + k];
      else if (k == 12) v2 = B2[8*t + row];
    }
    a2[r] = (_Float16)v2;

    float v3 = 0.f;
    if (row == 0 && k < 8) v3 = W3[t * (8*NTOW) + 8*t + k];
    a3[r] = (_Float16)v3;
  }
  store_frag(rec +          2*l, a0);
  store_frag(rec + OFF_A1 + 2*l, a1);
  store_frag(rec + OFF_A2 + 2*l, a2);
  store_frag(rec + OFF_A3 + 2*l, a3);

  if (l < 16) {
    const float bv = (l < 12) ? B1[12*t + l] : 0.f;
    rec[OFF_B1 + l] = __float_as_uint(bv);
  }
  if (t == 0 && l == 0) {
    float s = bias[0];
    for (int j = 0; j < NTOW; ++j) s += B3[j];
    pack[NTOW * REC] = __float_as_uint(s);
  }
}

// One wave: tower group g (16 towers), U tiles of 16 samples.
__global__ __launch_bounds__(256, 8) void bs_mfma(
    const float* __restrict__ x, const uint32_t* __restrict__ pack,
    float* __restrict__ out) {
  const int wid   = blockIdx.x * 4 + (threadIdx.x >> 6);
  const int lane  = threadIdx.x & 63;
  const int col   = lane & 15;       // sample within tile
  const int kg    = lane >> 4;
  const int g     = wid & 7;         // tower group: towers [16g, 16g+16)
  const int sbase = (wid >> 3) * (16 * U);

  const float cbias = __uint_as_float(pack[NTOW * REC]);
  const f4_t zc = {0.f, 0.f, 0.f, 0.f};

  f4_t acc[U];
#pragma unroll
  for (int u = 0; u < U; ++u) acc[u] = zc;

  // Per-lane x base: sample row (sbase+col), feature 2*(16g + kg).
  const float* __restrict__ xb =
      x + (size_t)(sbase + col) * FEAT + 2 * (g * 16 + kg);

#pragma unroll
  for (int p = 0; p < 4; ++p) {      // packs of 4 towers
    // Shared B0 for 4 towers: lane (kg,col) holds tower tb+kg's x pair.
    h4_t b0[U];
#pragma unroll
    for (int u = 0; u < U; ++u) {
      const float2 xv = *(const float2*)(xb + 8 * p + (size_t)u * 16 * FEAT);
      const hp2_t xh = __builtin_amdgcn_cvt_pkrtz(xv.x, xv.y);
      b0[u][0] = (_Float16)xh[0];
      b0[u][1] = (_Float16)xh[1];
      b0[u][2] = (_Float16)1.0f;
      b0[u][3] = (_Float16)0.0f;
    }

#pragma unroll
    for (int j = 0; j < 4; ++j) {
      const int tower = g * 16 + p * 4 + j;
      const uint32_t* rec = pack + tower * REC;
      const h4_t a0 = load_frag(rec +          2*lane);
      const h4_t a1 = load_frag(rec + OFF_A1 + 2*lane);
      const h4_t a2 = load_frag(rec + OFF_A2 + 2*lane);
      const h4_t a3 = load_frag(rec + OFF_A3 + 2*lane);
      const float4 bb = *(const float4*)((const float*)rec + OFF_B1 + kg*4);
      const f4_t c1 = {bb.x, bb.y, bb.z, bb.w};

#pragma unroll
      for (int u = 0; u < U; ++u) {
        const f4_t d0 = __builtin_amdgcn_mfma_f32_16x16x16f16(a0, b0[u], zc, 0, 0, 0);
        const h4_t h0 = relu_pack4(d0);

        const f4_t d1 = __builtin_amdgcn_mfma_f32_16x16x16f16(a1, h0, c1, 0, 0, 0);
        h4_t h1 = relu_pack4(d1);
        if (kg == 3) h1[0] = (_Float16)1.0f;   // k=12 bias slot for layer 2

        const f4_t d2 = __builtin_amdgcn_mfma_f32_16x16x16f16(a2, h1, zc, 0, 0, 0);
        const h4_t h2 = relu_pack4(d2);

        acc[u] = __builtin_amdgcn_mfma_f32_16x16x16f16(a3, h2, acc[u], 0, 0, 0);
      }
    }
  }

  if (kg == 0) {
    const float add = (g == 0) ? cbias : 0.f;
#pragma unroll
    for (int u = 0; u < U; ++u)
      atomicAdd(out + sbase + u * 16 + col, acc[u][0] + add);
  }
}

// ---- correctness-only fallback (ws too small; never expected) ----
__device__ __forceinline__ float gather_weight(
    int t, int i,
    const float* __restrict__ W0, const float* __restrict__ B0,
    const float* __restrict__ W1, const float* __restrict__ B1,
    const float* __restrict__ W2, const float* __restrict__ B2,
    const float* __restrict__ W3, const float* __restrict__ B3) {
  float v = 0.f;
  if (i < 32)       { int r = i >> 1, c = i & 1;               v = W0[(16*t + r)*FEAT + 2*t + c]; }
  else if (i < 48)  {                                           v = B0[16*t + (i - 32)]; }
  else if (i < 240) { int k = i - 48, r = k >> 4, c = k & 15;   v = W1[(12*t + r)*(16*NTOW) + 16*t + c]; }
  else if (i < 252) {                                           v = B1[12*t + (i - 240)]; }
  else if (i < 348) { int k = i - 252, r = k / 12, c = k - 12*r; v = W2[(8*t + r)*(12*NTOW) + 12*t + c]; }
  else if (i < 356) {                                           v = B2[8*t + (i - 348)]; }
  else if (i < 364) {                                           v = W3[t*(8*NTOW) + 8*t + (i - 356)]; }
  else if (i == 364){                                           v = B3[t]; }
  return v;
}

__global__ void bs_fwd_slow(
    const float* __restrict__ x,
    const float* __restrict__ W0, const float* __restrict__ B0,
    const float* __restrict__ W1, const float* __restrict__ B1,
    const float* __restrict__ W2, const float* __restrict__ B2,
    const float* __restrict__ W3, const float* __restrict__ B3,
    const float* __restrict__ bias,
    float* __restrict__ out) {
  const int s = blockIdx.x * blockDim.x + threadIdx.x;
  if (s >= BATCH) return;
  float acc = bias[0];
  for (int t = 0; t < NTOW; ++t) {
    float h0[16], h1[12], h2[8];
    const float x0 = x[(size_t)s*FEAT + 2*t], x1 = x[(size_t)s*FEAT + 2*t + 1];
    for (int r = 0; r < 16; ++r)
      h0[r] = fmaxf(0.f, gather_weight(t, 2*r, W0,B0,W1,B1,W2,B2,W3,B3) * x0
                        + gather_weight(t, 2*r+1, W0,B0,W1,B1,W2,B2,W3,B3) * x1
                        + gather_weight(t, 32+r, W0,B0,W1,B1,W2,B2,W3,B3));
    for (int r = 0; r < 12; ++r) {
      float sum = gather_weight(t, 240+r, W0,B0,W1,B1,W2,B2,W3,B3);
      for (int c = 0; c < 16; ++c)
        sum += gather_weight(t, 48+16*r+c, W0,B0,W1,B1,W2,B2,W3,B3) * h0[c];
      h1[r] = fmaxf(0.f, sum);
    }
    for (int r = 0; r < 8; ++r) {
      float sum = gather_weight(t, 348+r, W0,B0,W1,B1,W2,B2,W3,B3);
      for (int c = 0; c < 12; ++c)
        sum += gather_weight(t, 252+12*r+c, W0,B0,W1,B1,W2,B2,W3,B3) * h1[c];
      h2[r] = fmaxf(0.f, sum);
    }
    float sum = gather_weight(t, 364, W0,B0,W1,B1,W2,B2,W3,B3);
    for (int c = 0; c < 8; ++c)
      sum += gather_weight(t, 356+c, W0,B0,W1,B1,W2,B2,W3,B3) * h2[c];
    acc += sum;
  }
  out[s] = acc;
}

extern "C" void kernel_launch(void* const* d_in, const int* in_sizes, int n_in,
                              void* d_out, int out_size, void* d_ws, size_t ws_size,
                              hipStream_t stream) {
  const float* x    = (const float*)d_in[0];
  const float* W0   = (const float*)d_in[1];
  const float* B0   = (const float*)d_in[2];
  const float* W1   = (const float*)d_in[3];
  const float* B1   = (const float*)d_in[4];
  const float* W2   = (const float*)d_in[5];
  const float* B2   = (const float*)d_in[6];
  const float* W3   = (const float*)d_in[7];
  const float* B3   = (const float*)d_in[8];
  const float* bias = (const float*)d_in[9];
  float* out = (float*)d_out;

  // Zero outputs: out[0:32768] accumulated via atomics, shape_loss[128] stays 0.
  (void)hipMemsetAsync(d_out, 0, (size_t)out_size * sizeof(float), stream);

  const size_t packBytes = ((size_t)NTOW * REC + 1) * sizeof(uint32_t);

  if (ws_size >= packBytes) {
    uint32_t* pack = (uint32_t*)d_ws;
    pack_frags<<<NTOW, 64, 0, stream>>>(W0, B0, W1, B1, W2, B2, W3, B3, bias, pack);
    const int waves = (BATCH / (16 * U)) * 8;     // 8192 waves
    bs_mfma<<<waves / 4, 256, 0, stream>>>(x, pack, out);
  } else {
    bs_fwd_slow<<<BATCH / 256, 256, 0, stream>>>(x, W0, B0, W1, B1, W2, B2, W3, B3, bias, out);
  }
}

// Round 7
// 36.072 us; speedup vs baseline: 1.2308x; 1.2308x over previous
//
#include <hip/hip_runtime.h>
#include <stdint.h>

// Blocksparse Deep ReLU GAM forward via chained f16 MFMA.
// 128 towers, each 2->16->12->8->1 MLP over input pair (2t, 2t+1);
// out[s] = sum_t tower_t(x[s]) + bias. shape_loss output = zeros(128).
//
// v_mfma_f32_16x16x16_f16 D layout (row=(lane>>4)*4+reg, col=lane&15)
// equals the B layout (k=(lane>>4)*4+i, col=lane&15), so Y = W·X chains
// layer-to-layer with only lane-local relu + f32->f16 cvt.
//
// Round 7: latency-oriented restructure.
//  - Interleaved tower record: per lane 8 contiguous dwords
//    [a0|a1|a2|a3] -> two dwordx4 loads (was 4x dwordx2 at 1KB strides).
//  - Explicit register double-buffer across the 16 towers: tower j+1's
//    3 loads issue before tower j's 16-MFMA body (covers L2 latency).
//  - All 16 B0 fragments (4 packs x U tiles) preloaded up front.
//  - U=4 (64 samples/wave), 4096 waves, launch_bounds(256,4) = 128 VGPR
//    so the pipelining actually has register headroom (r4/5 compiled to
//    32 VGPR -> no load hoisting -> exposed L2 latency per tower).
//
// 4-tower shared B0: lane (kg,col) carries B0 rows 4kg..4kg+2 =
// {x[s][2(tb+kg)], x[s][2(tb+kg)+1], 1}; tower tb+j's A0 is nonzero only
// in k-columns 4j..4j+2, so one coalesced all-lane x load feeds 4 towers.
//
// Bias: b0 -> A0 k=4j+2 (homogeneous coord); b1 -> C of layer-1 MFMA;
// b2 -> A2 column k=12 with h1[12]=1 (rows 12..15 of h1 are structurally
// zero); sum_t b3[t] + bias -> one scalar at the end.

constexpr int BATCH = 32768;
constexpr int FEAT  = 256;
constexpr int NTOW  = 128;
constexpr int U     = 4;    // 16-sample tiles per wave

constexpr int REC = 528;  // dwords per tower record (2112 B, 16B-aligned)
// record layout (dword offsets): [0,512) = 64 lanes x 8 dwords
// {a0.lo,a0.hi,a1.lo,a1.hi,a2.lo,a2.hi,a3.lo,a3.hi}; [512,528) = b1 f32[16].
constexpr int OFF_B1 = 512;

typedef _Float16 h4_t __attribute__((ext_vector_type(4)));
typedef __fp16   hp2_t __attribute__((ext_vector_type(2)));
typedef float    f4_t __attribute__((ext_vector_type(4)));

static __device__ __forceinline__ h4_t u2_to_h4(uint32_t lo, uint32_t hi) {
  union { uint2 u; h4_t h; } cv; cv.u.x = lo; cv.u.y = hi; return cv.h;
}
static __device__ __forceinline__ void h4_to_u2(h4_t v, uint32_t* d) {
  union { h4_t h; uint2 u; } cv; cv.h = v; d[0] = cv.u.x; d[1] = cv.u.y;
}
// pack 4 f32 -> 4 f16 (2x v_cvt_pkrtz) then packed relu (v_pk_max_f16 x2).
// relu(cvt(x)) == cvt(relu(x)): RTZ preserves sign; -0 is harmless in dots.
static __device__ __forceinline__ h4_t relu_pack4(const f4_t d) {
  const hp2_t lo = __builtin_amdgcn_cvt_pkrtz(d[0], d[1]);
  const hp2_t hi = __builtin_amdgcn_cvt_pkrtz(d[2], d[3]);
  h4_t r;
  r[0] = (_Float16)lo[0]; r[1] = (_Float16)lo[1];
  r[2] = (_Float16)hi[0]; r[3] = (_Float16)hi[1];
  const h4_t z = {(_Float16)0.f, (_Float16)0.f, (_Float16)0.f, (_Float16)0.f};
  return __builtin_elementwise_max(r, z);
}

__global__ void pack_frags(
    const float* __restrict__ W0, const float* __restrict__ B0,
    const float* __restrict__ W1, const float* __restrict__ B1,
    const float* __restrict__ W2, const float* __restrict__ B2,
    const float* __restrict__ W3, const float* __restrict__ B3,
    const float* __restrict__ bias, uint32_t* __restrict__ pack) {
  const int t   = blockIdx.x;
  const int l   = threadIdx.x;      // 64 threads = 64 lanes
  const int row = l & 15;           // A-frag row  = lane&15
  const int kg  = l >> 4;           // A-frag k    = (lane>>4)*4 + r
  uint32_t* rec = pack + t * REC;

  h4_t a0, a1, a2, a3;
#pragma unroll
  for (int r = 0; r < 4; ++r) {
    const int k = kg * 4 + r;
    // A0: tower t occupies k-columns 4*(t&3) .. 4*(t&3)+2.
    float v0 = 0.f;
    if (kg == (t & 3)) {
      if (r < 2)       v0 = W0[(16*t + row) * FEAT + 2*t + r];
      else if (r == 2) v0 = B0[16*t + row];
    }
    a0[r] = (_Float16)v0;

    float v1 = 0.f;
    if (row < 12)    v1 = W1[(12*t + row) * (16*NTOW) + 16*t + k];
    a1[r] = (_Float16)v1;

    float v2 = 0.f;
    if (row < 8) {
      if (k < 12)       v2 = W2[(8*t + row) * (12*NTOW) + 12*t + k];
      else if (k == 12) v2 = B2[8*t + row];
    }
    a2[r] = (_Float16)v2;

    float v3 = 0.f;
    if (row == 0 && k < 8) v3 = W3[t * (8*NTOW) + 8*t + k];
    a3[r] = (_Float16)v3;
  }
  uint32_t* lrec = rec + 8 * l;
  h4_to_u2(a0, lrec + 0);
  h4_to_u2(a1, lrec + 2);
  h4_to_u2(a2, lrec + 4);
  h4_to_u2(a3, lrec + 6);

  if (l < 16) {
    const float bv = (l < 12) ? B1[12*t + l] : 0.f;
    rec[OFF_B1 + l] = __float_as_uint(bv);
  }
  if (t == 0 && l == 0) {
    float s = bias[0];
    for (int j = 0; j < NTOW; ++j) s += B3[j];
    pack[NTOW * REC] = __float_as_uint(s);
  }
}

// One wave: tower group g (16 towers), U tiles of 16 samples.
__global__ __launch_bounds__(256, 4) void bs_mfma(
    const float* __restrict__ x, const uint32_t* __restrict__ pack,
    float* __restrict__ out) {
  const int wid   = blockIdx.x * 4 + (threadIdx.x >> 6);
  const int lane  = threadIdx.x & 63;
  const int col   = lane & 15;       // sample within tile
  const int kg    = lane >> 4;
  const int g     = wid & 7;         // tower group: towers [16g, 16g+16)
  const int sbase = (wid >> 3) * (16 * U);

  const float cbias = __uint_as_float(pack[NTOW * REC]);
  const f4_t zc = {0.f, 0.f, 0.f, 0.f};

  f4_t acc[U];
#pragma unroll
  for (int u = 0; u < U; ++u) acc[u] = zc;

  // ---- preload all 16 B0 fragments (4 packs x U tiles) ----
  // Per-lane x base: sample row (sbase+col), feature 2*(16g + kg).
  const float* __restrict__ xb =
      x + (size_t)(sbase + col) * FEAT + 2 * (g * 16 + kg);
  h4_t b0[4 * U];
#pragma unroll
  for (int p = 0; p < 4; ++p)
#pragma unroll
    for (int u = 0; u < U; ++u) {
      const float2 xv = *(const float2*)(xb + 8 * p + (size_t)u * 16 * FEAT);
      const hp2_t xh = __builtin_amdgcn_cvt_pkrtz(xv.x, xv.y);
      h4_t b;
      b[0] = (_Float16)xh[0];
      b[1] = (_Float16)xh[1];
      b[2] = (_Float16)1.0f;
      b[3] = (_Float16)0.0f;
      b0[p * U + u] = b;
    }

  // ---- tower loop with register double-buffer of weight frags ----
  const uint32_t* __restrict__ fp = pack + (size_t)(g * 16) * REC + 8 * lane;
  const uint32_t* __restrict__ bp = pack + (size_t)(g * 16) * REC + OFF_B1 + kg * 4;

  uint4  f01 = *(const uint4*)fp;
  uint4  f23 = *(const uint4*)(fp + 4);
  float4 bb  = *(const float4*)bp;

#pragma unroll
  for (int j = 0; j < 16; ++j) {
    uint4 nf01, nf23; float4 nbb;
    if (j < 15) {
      nf01 = *(const uint4*)(fp + (j + 1) * REC);
      nf23 = *(const uint4*)(fp + (j + 1) * REC + 4);
      nbb  = *(const float4*)(bp + (j + 1) * REC);
    }

    const h4_t a0 = u2_to_h4(f01.x, f01.y);
    const h4_t a1 = u2_to_h4(f01.z, f01.w);
    const h4_t a2 = u2_to_h4(f23.x, f23.y);
    const h4_t a3 = u2_to_h4(f23.z, f23.w);
    const f4_t c1 = {bb.x, bb.y, bb.z, bb.w};
    const int  p  = j >> 2;

#pragma unroll
    for (int u = 0; u < U; ++u) {
      const f4_t d0 = __builtin_amdgcn_mfma_f32_16x16x16f16(a0, b0[p * U + u], zc, 0, 0, 0);
      const h4_t h0 = relu_pack4(d0);

      const f4_t d1 = __builtin_amdgcn_mfma_f32_16x16x16f16(a1, h0, c1, 0, 0, 0);
      h4_t h1 = relu_pack4(d1);
      if (kg == 3) h1[0] = (_Float16)1.0f;   // k=12 bias slot for layer 2

      const f4_t d2 = __builtin_amdgcn_mfma_f32_16x16x16f16(a2, h1, zc, 0, 0, 0);
      const h4_t h2 = relu_pack4(d2);

      acc[u] = __builtin_amdgcn_mfma_f32_16x16x16f16(a3, h2, acc[u], 0, 0, 0);
    }

    if (j < 15) { f01 = nf01; f23 = nf23; bb = nbb; }
  }

  if (kg == 0) {
    const float add = (g == 0) ? cbias : 0.f;
#pragma unroll
    for (int u = 0; u < U; ++u)
      atomicAdd(out + sbase + u * 16 + col, acc[u][0] + add);
  }
}

// ---- correctness-only fallback (ws too small; never expected) ----
__device__ __forceinline__ float gather_weight(
    int t, int i,
    const float* __restrict__ W0, const float* __restrict__ B0,
    const float* __restrict__ W1, const float* __restrict__ B1,
    const float* __restrict__ W2, const float* __restrict__ B2,
    const float* __restrict__ W3, const float* __restrict__ B3) {
  float v = 0.f;
  if (i < 32)       { int r = i >> 1, c = i & 1;               v = W0[(16*t + r)*FEAT + 2*t + c]; }
  else if (i < 48)  {                                           v = B0[16*t + (i - 32)]; }
  else if (i < 240) { int k = i - 48, r = k >> 4, c = k & 15;   v = W1[(12*t + r)*(16*NTOW) + 16*t + c]; }
  else if (i < 252) {                                           v = B1[12*t + (i - 240)]; }
  else if (i < 348) { int k = i - 252, r = k / 12, c = k - 12*r; v = W2[(8*t + r)*(12*NTOW) + 12*t + c]; }
  else if (i < 356) {                                           v = B2[8*t + (i - 348)]; }
  else if (i < 364) {                                           v = W3[t*(8*NTOW) + 8*t + (i - 356)]; }
  else if (i == 364){                                           v = B3[t]; }
  return v;
}

__global__ void bs_fwd_slow(
    const float* __restrict__ x,
    const float* __restrict__ W0, const float* __restrict__ B0,
    const float* __restrict__ W1, const float* __restrict__ B1,
    const float* __restrict__ W2, const float* __restrict__ B2,
    const float* __restrict__ W3, const float* __restrict__ B3,
    const float* __restrict__ bias,
    float* __restrict__ out) {
  const int s = blockIdx.x * blockDim.x + threadIdx.x;
  if (s >= BATCH) return;
  float acc = bias[0];
  for (int t = 0; t < NTOW; ++t) {
    float h0[16], h1[12], h2[8];
    const float x0 = x[(size_t)s*FEAT + 2*t], x1 = x[(size_t)s*FEAT + 2*t + 1];
    for (int r = 0; r < 16; ++r)
      h0[r] = fmaxf(0.f, gather_weight(t, 2*r, W0,B0,W1,B1,W2,B2,W3,B3) * x0
                        + gather_weight(t, 2*r+1, W0,B0,W1,B1,W2,B2,W3,B3) * x1
                        + gather_weight(t, 32+r, W0,B0,W1,B1,W2,B2,W3,B3));
    for (int r = 0; r < 12; ++r) {
      float sum = gather_weight(t, 240+r, W0,B0,W1,B1,W2,B2,W3,B3);
      for (int c = 0; c < 16; ++c)
        sum += gather_weight(t, 48+16*r+c, W0,B0,W1,B1,W2,B2,W3,B3) * h0[c];
      h1[r] = fmaxf(0.f, sum);
    }
    for (int r = 0; r < 8; ++r) {
      float sum = gather_weight(t, 348+r, W0,B0,W1,B1,W2,B2,W3,B3);
      for (int c = 0; c < 12; ++c)
        sum += gather_weight(t, 252+12*r+c, W0,B0,W1,B1,W2,B2,W3,B3) * h1[c];
      h2[r] = fmaxf(0.f, sum);
    }
    float sum = gather_weight(t, 364, W0,B0,W1,B1,W2,B2,W3,B3);
    for (int c = 0; c < 8; ++c)
      sum += gather_weight(t, 356+c, W0,B0,W1,B1,W2,B2,W3,B3) * h2[c];
    acc += sum;
  }
  out[s] = acc;
}

extern "C" void kernel_launch(void* const* d_in, const int* in_sizes, int n_in,
                              void* d_out, int out_size, void* d_ws, size_t ws_size,
                              hipStream_t stream) {
  const float* x    = (const float*)d_in[0];
  const float* W0   = (const float*)d_in[1];
  const float* B0   = (const float*)d_in[2];
  const float* W1   = (const float*)d_in[3];
  const float* B1   = (const float*)d_in[4];
  const float* W2   = (const float*)d_in[5];
  const float* B2   = (const float*)d_in[6];
  const float* W3   = (const float*)d_in[7];
  const float* B3   = (const float*)d_in[8];
  const float* bias = (const float*)d_in[9];
  float* out = (float*)d_out;

  // Zero outputs: out[0:32768] accumulated via atomics, shape_loss[128] stays 0.
  (void)hipMemsetAsync(d_out, 0, (size_t)out_size * sizeof(float), stream);

  const size_t packBytes = ((size_t)NTOW * REC + 1) * sizeof(uint32_t);

  if (ws_size >= packBytes) {
    uint32_t* pack = (uint32_t*)d_ws;
    pack_frags<<<NTOW, 64, 0, stream>>>(W0, B0, W1, B1, W2, B2, W3, B3, bias, pack);
    const int waves = (BATCH / (16 * U)) * 8;     // 4096 waves
    bs_mfma<<<waves / 4, 256, 0, stream>>>(x, pack, out);
  } else {
    bs_fwd_slow<<<BATCH / 256, 256, 0, stream>>>(x, W0, B0, W1, B1, W2, B2, W3, B3, bias, out);
  }
}